// Round 1
// baseline (1015.261 us; speedup 1.0000x reference)
//
#include <hip/hip_runtime.h>
#include <hip/hip_bf16.h>
#include <stdint.h>

using u16 = unsigned short;
using u32 = unsigned int;

typedef __attribute__((ext_vector_type(8))) short short8;
typedef __attribute__((ext_vector_type(4))) float floatx4;

__device__ __forceinline__ u16 f2bf(float f) {
  __hip_bfloat16 h = __float2bfloat16(f);
  return *reinterpret_cast<u16*>(&h);
}

__device__ __forceinline__ void gl_lds16(const void* g, void* l) {
  __builtin_amdgcn_global_load_lds((const __attribute__((address_space(1))) void*)g,
                                   (__attribute__((address_space(3))) void*)l, 16, 0, 0);
}

// ---------------- transpose fp32 [R][Cc] -> bf16 [Cc][R] ----------------
__global__ __launch_bounds__(256)
void transpose_to_bf16(const float* __restrict__ in, u16* __restrict__ out,
                       int R, int Cc) {
  __shared__ float tile[32][33];
  int c0 = blockIdx.x * 32;
  int r0 = blockIdx.y * 32;
  int tx = threadIdx.x;   // 0..31
  int ty = threadIdx.y;   // 0..7
#pragma unroll
  for (int i = 0; i < 32; i += 8)
    tile[ty + i][tx] = in[(size_t)(r0 + ty + i) * Cc + c0 + tx];
  __syncthreads();
#pragma unroll
  for (int i = 0; i < 32; i += 8)
    out[(size_t)(c0 + ty + i) * R + r0 + tx] = f2bf(tile[tx][ty + i]);
}

// ---------------- elementwise fp32 -> bf16 ----------------
__global__ __launch_bounds__(256)
void cvt_bf16(const float4* __restrict__ in, uint2* __restrict__ out, int n4) {
  int i = blockIdx.x * 256 + threadIdx.x;
  if (i >= n4) return;
  float4 v = in[i];
  u32 lo = (u32)f2bf(v.x) | ((u32)f2bf(v.y) << 16);
  u32 hi = (u32)f2bf(v.z) | ((u32)f2bf(v.w) << 16);
  out[i] = make_uint2(lo, hi);
}

// ---------------- GEMM: C[M][N] = A[M][K] @ BT[N][K]^T + bias ----------------
constexpr int BM = 128, BN = 128, BK = 32;

template <bool A_BF16, bool RELU>
__global__ __launch_bounds__(256, 3)
void gemm_bt(const void* __restrict__ Aip, const u16* __restrict__ BT,
             const float* __restrict__ bias, u16* __restrict__ C,
             int M, int N, int K) {
  __shared__ __align__(16) u16 As[BM * BK];
  __shared__ __align__(16) u16 Bs[BN * BK];
  const int tid  = threadIdx.x;
  const int lane = tid & 63;
  const int wave = tid >> 6;
  const int m0 = blockIdx.y * BM;
  const int n0 = blockIdx.x * BN;
  const int wm = (wave & 1) * 64;
  const int wn = (wave >> 1) * 64;
  const int row = lane & 15;   // m (A) / n (B) within 16
  const int kq  = lane >> 4;   // k-quad 0..3 (8 bf16 each)

  floatx4 acc[4][4] = {};

  // fragment LDS offsets (ushort units), XOR-swizzled chunk placement
  int a_off[4], b_off[4];
#pragma unroll
  for (int t = 0; t < 4; ++t) {
    int mr = wm + t * 16 + row;
    a_off[t] = mr * BK + ((kq ^ ((mr >> 1) & 3)) * 8);
    int nr = wn + t * 16 + row;
    b_off[t] = nr * BK + ((kq ^ ((nr >> 1) & 3)) * 8);
  }

  // B staging: 512 x 16B chunks per tile via global_load_lds
  const u16* bptr[2];
  int b_lds[2];
#pragma unroll
  for (int it = 0; it < 2; ++it) {
    int c = it * 256 + tid;
    int nrow = c >> 2;
    int kc = ((c & 3) ^ ((nrow >> 1) & 3)) * 8;
    bptr[it] = BT + (size_t)(n0 + nrow) * K + kc;
    b_lds[it] = (it * 256 + wave * 64) * 8;  // wave-uniform base (ushorts)
  }

  // A staging
  const u16* aptrB[2];
  int a_ldsB[2];
  const float* aptrF[4];
  int a_stF[4];
  if constexpr (A_BF16) {
    const u16* A = (const u16*)Aip;
#pragma unroll
    for (int it = 0; it < 2; ++it) {
      int c = it * 256 + tid;
      int mrow = c >> 2;
      int kc = ((c & 3) ^ ((mrow >> 1) & 3)) * 8;
      aptrB[it] = A + (size_t)(m0 + mrow) * K + kc;
      a_ldsB[it] = (it * 256 + wave * 64) * 8;
    }
  } else {
    const float* A = (const float*)Aip;
#pragma unroll
    for (int it = 0; it < 4; ++it) {
      int idx = it * 256 + tid;
      int mrow = idx >> 3;
      int kc = (idx & 7) * 4;  // 4 floats
      aptrF[it] = A + (size_t)(m0 + mrow) * K + kc;
      int chunk = kc >> 3, half = (kc >> 2) & 1;
      int sc = chunk ^ ((mrow >> 1) & 3);
      a_stF[it] = mrow * BK + sc * 8 + half * 4;
    }
  }

  for (int k0 = 0; k0 < K; k0 += BK) {
    __syncthreads();
    if constexpr (A_BF16) {
#pragma unroll
      for (int it = 0; it < 2; ++it)
        gl_lds16(aptrB[it] + k0, &As[a_ldsB[it]]);
    } else {
#pragma unroll
      for (int it = 0; it < 4; ++it) {
        float4 v = *(const float4*)(aptrF[it] + k0);
        u32 lo = (u32)f2bf(v.x) | ((u32)f2bf(v.y) << 16);
        u32 hi = (u32)f2bf(v.z) | ((u32)f2bf(v.w) << 16);
        *(uint2*)&As[a_stF[it]] = make_uint2(lo, hi);
      }
    }
#pragma unroll
    for (int it = 0; it < 2; ++it)
      gl_lds16(bptr[it] + k0, &Bs[b_lds[it]]);
    __syncthreads();

    short8 a[4], b[4];
#pragma unroll
    for (int t = 0; t < 4; ++t) {
      a[t] = *(const short8*)&As[a_off[t]];
      b[t] = *(const short8*)&Bs[b_off[t]];
    }
#pragma unroll
    for (int mt = 0; mt < 4; ++mt)
#pragma unroll
      for (int nt = 0; nt < 4; ++nt)
        acc[mt][nt] = __builtin_amdgcn_mfma_f32_16x16x32_bf16(
            a[mt], b[nt], acc[mt][nt], 0, 0, 0);
  }

  // epilogue: C/D layout col=lane&15, row=(lane>>4)*4+r
  const int ccol = row;
  const int crow = kq * 4;
#pragma unroll
  for (int mt = 0; mt < 4; ++mt) {
#pragma unroll
    for (int nt = 0; nt < 4; ++nt) {
      int gm = m0 + wm + mt * 16 + crow;
      int gn = n0 + wn + nt * 16 + ccol;
      float bv = bias[gn];
#pragma unroll
      for (int r = 0; r < 4; ++r) {
        float v = acc[mt][nt][r] + bv;
        if (RELU) v = fmaxf(v, 0.f);
        C[(size_t)(gm + r) * N + gn] = f2bf(v);
      }
    }
  }
}

// ---------------- heads: one wave per row ----------------
__device__ __forceinline__ float wave_sum(float v) {
#pragma unroll
  for (int m = 32; m >= 1; m >>= 1) v += __shfl_xor(v, m, 64);
  return v;
}

__global__ __launch_bounds__(64)
void head_kernel(const u16* __restrict__ H, const float* __restrict__ Wc,
                 const float* __restrict__ bc, const float* __restrict__ Wr,
                 const float* __restrict__ br, float* __restrict__ out) {
  const int rowi = blockIdx.x;
  const int lane = threadIdx.x;
  const u16* h = H + (size_t)rowi * 1024 + lane * 16;
  uint4 p0 = *(const uint4*)h;
  uint4 p1 = *(const uint4*)(h + 8);
  u32 w[8] = {p0.x, p0.y, p0.z, p0.w, p1.x, p1.y, p1.z, p1.w};
  float x[16];
#pragma unroll
  for (int i = 0; i < 8; ++i) {
    union { u32 u; float f; } lo, hi;
    lo.u = w[i] << 16;
    hi.u = w[i] & 0xffff0000u;
    x[2 * i] = lo.f;
    x[2 * i + 1] = hi.f;
  }
  float ac[4] = {};
  float ar[12] = {};
  const int kbase = lane * 16;
#pragma unroll
  for (int j = 0; j < 16; ++j) {
    float xv = x[j];
    const float* wc = Wc + (size_t)(kbase + j) * 4;
#pragma unroll
    for (int c = 0; c < 4; ++c) ac[c] = fmaf(xv, wc[c], ac[c]);
    const float* wr = Wr + (size_t)(kbase + j) * 12;
#pragma unroll
    for (int r = 0; r < 12; ++r) ar[r] = fmaf(xv, wr[r], ar[r]);
  }
#pragma unroll
  for (int c = 0; c < 4; ++c) ac[c] = wave_sum(ac[c]);
#pragma unroll
  for (int r = 0; r < 12; ++r) ar[r] = wave_sum(ar[r]);

  if (lane == 0) {
    float lg[4], mx = -1e30f;
#pragma unroll
    for (int c = 0; c < 4; ++c) { lg[c] = ac[c] + bc[c]; mx = fmaxf(mx, lg[c]); }
    float s = 0.f;
#pragma unroll
    for (int c = 0; c < 4; ++c) { lg[c] = __expf(lg[c] - mx); s += lg[c]; }
    float inv = 1.f / s;
#pragma unroll
    for (int c = 0; c < 4; ++c) out[(size_t)rowi * 4 + c] = lg[c] * inv;
    float* ob = out + 8192 * 4;
#pragma unroll
    for (int r = 0; r < 12; ++r) ob[(size_t)rowi * 12 + r] = ar[r] + br[r];
  }
}

extern "C" void kernel_launch(void* const* d_in, const int* in_sizes, int n_in,
                              void* d_out, int out_size, void* d_ws, size_t ws_size,
                              hipStream_t stream) {
  const float* X  = (const float*)d_in[0];
  const float* W1 = (const float*)d_in[1];
  const float* b1 = (const float*)d_in[2];
  const float* W2 = (const float*)d_in[3];
  const float* b2 = (const float*)d_in[4];
  const float* Wc = (const float*)d_in[5];
  const float* bc = (const float*)d_in[6];
  const float* Wr = (const float*)d_in[7];
  const float* br = (const float*)d_in[8];

  constexpr int NP = 8192, DIN = 12544, HID = 1024;
  char* ws = (char*)d_ws;
  u16* W1T = (u16*)ws;                                        // HID*DIN bf16
  u16* W2T = (u16*)(ws + (size_t)HID * DIN * 2);              // HID*HID
  u16* H1  = (u16*)((char*)W2T + (size_t)HID * HID * 2);      // NP*HID
  u16* Hb  = H1 + (size_t)NP * HID;                           // NP*HID
  u16* Xb  = Hb + (size_t)NP * HID;                           // NP*DIN (optional)
  size_t need_base = (size_t)HID * DIN * 2 + (size_t)HID * HID * 2 +
                     2 * (size_t)NP * HID * 2;
  bool use_xbf = ws_size >= need_base + (size_t)NP * DIN * 2;

  transpose_to_bf16<<<dim3(HID / 32, DIN / 32), dim3(32, 8), 0, stream>>>(W1, W1T, DIN, HID);
  transpose_to_bf16<<<dim3(HID / 32, HID / 32), dim3(32, 8), 0, stream>>>(W2, W2T, HID, HID);

  if (use_xbf) {
    int n4 = NP * DIN / 4;
    cvt_bf16<<<(n4 + 255) / 256, 256, 0, stream>>>((const float4*)X, (uint2*)Xb, n4);
    gemm_bt<true, false><<<dim3(HID / BN, NP / BM), 256, 0, stream>>>(
        Xb, W1T, b1, H1, NP, HID, DIN);
  } else {
    gemm_bt<false, false><<<dim3(HID / BN, NP / BM), 256, 0, stream>>>(
        X, W1T, b1, H1, NP, HID, DIN);
  }
  gemm_bt<true, true><<<dim3(HID / BN, NP / BM), 256, 0, stream>>>(
      H1, W2T, b2, Hb, NP, HID, HID);
  head_kernel<<<NP, 64, 0, stream>>>(Hb, Wc, bc, Wr, br, (float*)d_out);
}